// Round 2
// baseline (83.547 us; speedup 1.0000x reference)
//
#include <hip/hip_runtime.h>
#include <float.h>
#include <math.h>

#define PPIL   40000
#define NPTS   32
#define CIN    4
#define COUT   64
#define NBLK_A 1250            // PPIL / 32 pillars per block
#define LDS_PSTRIDE 292        // 32*9 = 288 floats + 4 pad (bank spread)

__device__ __forceinline__ float shfl_xor_f(float v, int m) {
    return __shfl_xor(v, m, 64);
}

// ---------------------------------------------------------------------------
// Kernel A: augment feats -> LDS, 9->64 matmul, per-pillar raw max (to d_out),
//           per-block partial sums of x and x^2 per channel (to ws).
// ---------------------------------------------------------------------------
__global__ __launch_bounds__(256) void pfn_main(
    const float* __restrict__ features,     // [P][N][4]
    const int*   __restrict__ num_voxels,   // [P]
    const int*   __restrict__ coors,        // [P][4]
    const float* __restrict__ linear_w,     // [64][9]
    float*       __restrict__ rawmax,       // [P][64]  (aliases d_out)
    float*       __restrict__ partials)     // [NBLK_A][128]
{
    __shared__ float lds_f[32 * LDS_PSTRIDE];
    __shared__ float lds_red[4][8][16];

    const int tid = threadIdx.x;
    const int bid = blockIdx.x;
    const int pillar_base = bid * 32;

    // ---- phase 1: compute masked augmented feats into LDS ----
    {
        const int n   = tid & 31;   // point index
        const int pl0 = tid >> 5;   // 0..7
        #pragma unroll
        for (int g = 0; g < 4; ++g) {
            const int pl = g * 8 + pl0;          // 0..31
            const int p  = pillar_base + pl;
            const float4 f = *(const float4*)(features + ((size_t)p * NPTS + n) * CIN);

            // pillar xyz sum over ALL 32 points (reference sums full N)
            float sx = f.x, sy = f.y, sz = f.z;
            #pragma unroll
            for (int m = 16; m >= 1; m >>= 1) {
                sx += shfl_xor_f(sx, m);
                sy += shfl_xor_f(sy, m);
                sz += shfl_xor_f(sz, m);
            }
            const int   nv     = num_voxels[p];
            const float inv_nv = 1.0f / (float)nv;
            const float mx_ = sx * inv_nv, my_ = sy * inv_nv, mz_ = sz * inv_nv;

            const int ccy = coors[p * 4 + 2];
            const int ccx = coors[p * 4 + 3];
            const float f7 = f.x - ((float)ccx * 0.2f + 0.1f);     // VX, X_OFF
            const float f8 = f.y - ((float)ccy * 0.2f - 39.9f);    // VY, Y_OFF

            const float msk = (n < nv) ? 1.0f : 0.0f;
            float* dst = &lds_f[pl * LDS_PSTRIDE + n * 9];
            dst[0] = f.x * msk;
            dst[1] = f.y * msk;
            dst[2] = f.z * msk;
            dst[3] = f.w * msk;
            dst[4] = (f.x - mx_) * msk;
            dst[5] = (f.y - my_) * msk;
            dst[6] = (f.z - mz_) * msk;
            dst[7] = f7 * msk;
            dst[8] = f8 * msk;
        }
    }
    __syncthreads();

    // ---- phase 2: 8 threads per pillar, 8 channels each (u = cg + 8k) ----
    const int pl2 = tid >> 3;   // pillar in block, 0..31
    const int cg  = tid & 7;    // channel group

    float w[8][9];
    #pragma unroll
    for (int k = 0; k < 8; ++k) {
        const float* wr = linear_w + (cg + 8 * k) * 9;
        #pragma unroll
        for (int c = 0; c < 9; ++c) w[k][c] = wr[c];
    }

    float s1[8], s2[8], mx[8];
    #pragma unroll
    for (int k = 0; k < 8; ++k) { s1[k] = 0.0f; s2[k] = 0.0f; mx[k] = -FLT_MAX; }

    const float* fbase = &lds_f[pl2 * LDS_PSTRIDE];
    for (int n = 0; n < NPTS; ++n) {
        const float* fp = fbase + n * 9;
        const float f0 = fp[0], f1 = fp[1], f2 = fp[2], f3 = fp[3], f4 = fp[4];
        const float f5 = fp[5], f6 = fp[6], f7 = fp[7], f8 = fp[8];
        #pragma unroll
        for (int k = 0; k < 8; ++k) {
            float x = w[k][0] * f0;
            x = fmaf(w[k][1], f1, x);
            x = fmaf(w[k][2], f2, x);
            x = fmaf(w[k][3], f3, x);
            x = fmaf(w[k][4], f4, x);
            x = fmaf(w[k][5], f5, x);
            x = fmaf(w[k][6], f6, x);
            x = fmaf(w[k][7], f7, x);
            x = fmaf(w[k][8], f8, x);
            s1[k] += x;
            s2[k] = fmaf(x, x, s2[k]);
            mx[k] = fmaxf(mx[k], x);
        }
    }

    // raw max -> rawmax (d_out), channel u = cg + 8k
    {
        float* rp = rawmax + (size_t)(pillar_base + pl2) * COUT + cg;
        #pragma unroll
        for (int k = 0; k < 8; ++k) rp[8 * k] = mx[k];
    }

    // reduce s1/s2 across lanes with equal (lane & 7)
    #pragma unroll
    for (int k = 0; k < 8; ++k) {
        #pragma unroll
        for (int m = 8; m <= 32; m <<= 1) {
            s1[k] += shfl_xor_f(s1[k], m);
            s2[k] += shfl_xor_f(s2[k], m);
        }
    }
    const int lane = tid & 63;
    const int wv   = tid >> 6;
    if (lane < 8) {
        #pragma unroll
        for (int k = 0; k < 8; ++k) {
            lds_red[wv][lane][k]     = s1[k];
            lds_red[wv][lane][8 + k] = s2[k];
        }
    }
    __syncthreads();
    if (tid < 128) {
        const int cg2 = tid >> 4, v = tid & 15;
        const float acc = lds_red[0][cg2][v] + lds_red[1][cg2][v] +
                          lds_red[2][cg2][v] + lds_red[3][cg2][v];
        partials[bid * 128 + tid] = acc;
    }
}

// ---------------------------------------------------------------------------
// Kernel B: parallel reduce of partials (double), finalize BN scale/bias.
// 1024 threads: value v = t&127, chunk j = t>>7 (8 chunks over 1250 rows).
// Coalesced: within a wave, 64 consecutive v at fixed row b.
// partial layout per row: [cg][k] = sum of channel u=cg+8k, [cg][8+k] = sumsq
// ---------------------------------------------------------------------------
__global__ __launch_bounds__(1024) void pfn_stats(
    const float* __restrict__ partials,
    const float* __restrict__ gamma,
    const float* __restrict__ beta,
    float*       __restrict__ stats)   // scale[64], bias[64]
{
    __shared__ double red[8][128];

    const int t = threadIdx.x;   // 0..1023
    const int v = t & 127;
    const int j = t >> 7;        // 0..7

    double acc = 0.0;
    for (int b = j; b < NBLK_A; b += 8)
        acc += (double)partials[b * 128 + v];
    red[j][v] = acc;
    __syncthreads();

    if (t < 128) {
        double s = 0.0;
        #pragma unroll
        for (int jj = 1; jj < 8; ++jj) s += red[jj][t];
        red[0][t] += s;
    }
    __syncthreads();

    if (t < 64) {
        const int cg = t & 7, k = t >> 3;       // u = cg + 8k
        const double s1 = red[0][cg * 16 + k];
        const double s2 = red[0][cg * 16 + 8 + k];
        const double PN = (double)PPIL * (double)NPTS;
        const double mean = s1 / PN;
        const double var  = s2 / PN - mean * mean;
        const double scale = (double)gamma[t] / sqrt(var + 1e-3);
        const double bias  = (double)beta[t] - mean * scale;
        stats[t]      = (float)scale;
        stats[64 + t] = (float)bias;
    }
}

// ---------------------------------------------------------------------------
// Kernel C: out = relu(rawmax * scale + bias), in place on d_out.
// ---------------------------------------------------------------------------
__global__ __launch_bounds__(256) void pfn_final(
    float* __restrict__ out,
    const float* __restrict__ stats,
    int total4)
{
    const int i = blockIdx.x * blockDim.x + threadIdx.x;
    if (i >= total4) return;
    const int u0 = (i & 15) * 4;     // 4 consecutive channels
    float4 v = ((float4*)out)[i];
    v.x = fmaxf(fmaf(v.x, stats[u0 + 0], stats[64 + u0 + 0]), 0.0f);
    v.y = fmaxf(fmaf(v.y, stats[u0 + 1], stats[64 + u0 + 1]), 0.0f);
    v.z = fmaxf(fmaf(v.z, stats[u0 + 2], stats[64 + u0 + 2]), 0.0f);
    v.w = fmaxf(fmaf(v.w, stats[u0 + 3], stats[64 + u0 + 3]), 0.0f);
    ((float4*)out)[i] = v;
}

// ---------------------------------------------------------------------------
extern "C" void kernel_launch(void* const* d_in, const int* in_sizes, int n_in,
                              void* d_out, int out_size, void* d_ws, size_t ws_size,
                              hipStream_t stream) {
    const float* features   = (const float*)d_in[0];
    const int*   num_voxels = (const int*)d_in[1];
    const int*   coors      = (const int*)d_in[2];
    const float* linear_w   = (const float*)d_in[3];
    const float* gamma      = (const float*)d_in[4];
    const float* beta       = (const float*)d_in[5];
    // d_in[6] = batch_size (unused)

    float* out = (float*)d_out;               // used as rawmax scratch, then finalized
    float* wsf = (float*)d_ws;
    float* partials = wsf;                    // NBLK_A * 128 floats = 640 KB
    float* stats    = wsf + NBLK_A * 128;     // 128 floats

    pfn_main<<<NBLK_A, 256, 0, stream>>>(features, num_voxels, coors, linear_w,
                                         out, partials);
    pfn_stats<<<1, 1024, 0, stream>>>(partials, gamma, beta, stats);

    const int total4 = PPIL * COUT / 4;       // 640000
    pfn_final<<<(total4 + 255) / 256, 256, 0, stream>>>(out, stats, total4);
}

// Round 3
// 47.482 us; speedup vs baseline: 1.7595x; 1.7595x over previous
//
#include <hip/hip_runtime.h>
#include <float.h>
#include <math.h>

#define PPIL   40000
#define NPTS   32
#define CIN    4
#define COUT   64
#define NBLK_A 1250            // PPIL / 32 pillars per block
#define LDS_PSTRIDE 292        // 32*9 = 288 floats + 4 pad (bank spread)

__device__ __forceinline__ float shfl_xor_f(float v, int m) {
    return __shfl_xor(v, m, 64);
}

// ---------------------------------------------------------------------------
// Kernel A: augment feats -> LDS, 9->64 matmul, per-pillar raw max (to d_out),
//           per-block partial sums of x and x^2 per channel (to ws).
// ---------------------------------------------------------------------------
__global__ __launch_bounds__(256) void pfn_main(
    const float* __restrict__ features,     // [P][N][4]
    const int*   __restrict__ num_voxels,   // [P]
    const int*   __restrict__ coors,        // [P][4]
    const float* __restrict__ linear_w,     // [64][9]
    float*       __restrict__ rawmax,       // [P][64]  (aliases d_out)
    float*       __restrict__ partials)     // [NBLK_A][128]
{
    __shared__ float lds_f[32 * LDS_PSTRIDE];
    __shared__ float lds_red[4][8][16];

    const int tid = threadIdx.x;
    const int bid = blockIdx.x;
    const int pillar_base = bid * 32;

    // ---- phase 1: compute masked augmented feats into LDS ----
    {
        const int n   = tid & 31;   // point index
        const int pl0 = tid >> 5;   // 0..7
        #pragma unroll
        for (int g = 0; g < 4; ++g) {
            const int pl = g * 8 + pl0;          // 0..31
            const int p  = pillar_base + pl;
            const float4 f = *(const float4*)(features + ((size_t)p * NPTS + n) * CIN);

            // pillar xyz sum over ALL 32 points (reference sums full N)
            float sx = f.x, sy = f.y, sz = f.z;
            #pragma unroll
            for (int m = 16; m >= 1; m >>= 1) {
                sx += shfl_xor_f(sx, m);
                sy += shfl_xor_f(sy, m);
                sz += shfl_xor_f(sz, m);
            }
            const int   nv     = num_voxels[p];
            const float inv_nv = 1.0f / (float)nv;
            const float mx_ = sx * inv_nv, my_ = sy * inv_nv, mz_ = sz * inv_nv;

            const int ccy = coors[p * 4 + 2];
            const int ccx = coors[p * 4 + 3];
            const float f7 = f.x - ((float)ccx * 0.2f + 0.1f);     // VX, X_OFF
            const float f8 = f.y - ((float)ccy * 0.2f - 39.9f);    // VY, Y_OFF

            const float msk = (n < nv) ? 1.0f : 0.0f;
            float* dst = &lds_f[pl * LDS_PSTRIDE + n * 9];
            dst[0] = f.x * msk;
            dst[1] = f.y * msk;
            dst[2] = f.z * msk;
            dst[3] = f.w * msk;
            dst[4] = (f.x - mx_) * msk;
            dst[5] = (f.y - my_) * msk;
            dst[6] = (f.z - mz_) * msk;
            dst[7] = f7 * msk;
            dst[8] = f8 * msk;
        }
    }
    __syncthreads();

    // ---- phase 2: 8 threads per pillar, 8 channels each (u = cg + 8k) ----
    const int pl2 = tid >> 3;   // pillar in block, 0..31
    const int cg  = tid & 7;    // channel group

    float w[8][9];
    #pragma unroll
    for (int k = 0; k < 8; ++k) {
        const float* wr = linear_w + (cg + 8 * k) * 9;
        #pragma unroll
        for (int c = 0; c < 9; ++c) w[k][c] = wr[c];
    }

    float s1[8], s2[8], mx[8];
    #pragma unroll
    for (int k = 0; k < 8; ++k) { s1[k] = 0.0f; s2[k] = 0.0f; mx[k] = -FLT_MAX; }

    const float* fbase = &lds_f[pl2 * LDS_PSTRIDE];
    for (int n = 0; n < NPTS; ++n) {
        const float* fp = fbase + n * 9;
        const float f0 = fp[0], f1 = fp[1], f2 = fp[2], f3 = fp[3], f4 = fp[4];
        const float f5 = fp[5], f6 = fp[6], f7 = fp[7], f8 = fp[8];
        #pragma unroll
        for (int k = 0; k < 8; ++k) {
            float x = w[k][0] * f0;
            x = fmaf(w[k][1], f1, x);
            x = fmaf(w[k][2], f2, x);
            x = fmaf(w[k][3], f3, x);
            x = fmaf(w[k][4], f4, x);
            x = fmaf(w[k][5], f5, x);
            x = fmaf(w[k][6], f6, x);
            x = fmaf(w[k][7], f7, x);
            x = fmaf(w[k][8], f8, x);
            s1[k] += x;
            s2[k] = fmaf(x, x, s2[k]);
            mx[k] = fmaxf(mx[k], x);
        }
    }

    // raw max -> rawmax (d_out), channel u = cg + 8k
    {
        float* rp = rawmax + (size_t)(pillar_base + pl2) * COUT + cg;
        #pragma unroll
        for (int k = 0; k < 8; ++k) rp[8 * k] = mx[k];
    }

    // reduce s1/s2 across lanes with equal (lane & 7)
    #pragma unroll
    for (int k = 0; k < 8; ++k) {
        #pragma unroll
        for (int m = 8; m <= 32; m <<= 1) {
            s1[k] += shfl_xor_f(s1[k], m);
            s2[k] += shfl_xor_f(s2[k], m);
        }
    }
    const int lane = tid & 63;
    const int wv   = tid >> 6;
    if (lane < 8) {
        #pragma unroll
        for (int k = 0; k < 8; ++k) {
            lds_red[wv][lane][k]     = s1[k];
            lds_red[wv][lane][8 + k] = s2[k];
        }
    }
    __syncthreads();
    if (tid < 128) {
        const int cg2 = tid >> 4, v = tid & 15;
        const float acc = lds_red[0][cg2][v] + lds_red[1][cg2][v] +
                          lds_red[2][cg2][v] + lds_red[3][cg2][v];
        partials[bid * 128 + tid] = acc;
    }
}

// ---------------------------------------------------------------------------
// Kernel B: parallel reduce of partials (double), finalize BN scale/bias.
// 1024 threads = 32 row-chunks (j = t>>5) x 32 float4-columns (col4 = t&31).
// Inner loop unrolled x4 with 4 independent float4 loads in flight per round
// -> hides the ~600-700 cy cross-XCD/L3 latency that serialized R1/R2.
// partial row layout: [cg][k] = sum of channel u=cg+8k, [cg][8+k] = sumsq
// ---------------------------------------------------------------------------
__global__ __launch_bounds__(1024) void pfn_stats(
    const float* __restrict__ partials,
    const float* __restrict__ gamma,
    const float* __restrict__ beta,
    float*       __restrict__ stats)   // scale[64], bias[64]
{
    __shared__ double red[32][128];

    const int t    = threadIdx.x;   // 0..1023
    const int col4 = t & 31;        // float4 column: channels v = col4*4 .. +3
    const int j    = t >> 5;        // row chunk 0..31

    const float4* p4 = (const float4*)partials;   // [NBLK_A][32] float4 rows

    double a0 = 0.0, a1 = 0.0, a2 = 0.0, a3 = 0.0;

    // rows b = j + 32*i, i = 0..39 (b < 1250). 36 unguarded in x4 rounds.
    int i = 0;
    for (; i + 4 <= 36; i += 4) {
        const float4 r0 = p4[(j + 32 * (i + 0)) * 32 + col4];
        const float4 r1 = p4[(j + 32 * (i + 1)) * 32 + col4];
        const float4 r2 = p4[(j + 32 * (i + 2)) * 32 + col4];
        const float4 r3 = p4[(j + 32 * (i + 3)) * 32 + col4];
        a0 += (double)r0.x + (double)r1.x + (double)r2.x + (double)r3.x;
        a1 += (double)r0.y + (double)r1.y + (double)r2.y + (double)r3.y;
        a2 += (double)r0.z + (double)r1.z + (double)r2.z + (double)r3.z;
        a3 += (double)r0.w + (double)r1.w + (double)r2.w + (double)r3.w;
    }
    for (; i < 40; ++i) {
        const int b = j + 32 * i;
        if (b < NBLK_A) {
            const float4 r = p4[b * 32 + col4];
            a0 += (double)r.x; a1 += (double)r.y;
            a2 += (double)r.z; a3 += (double)r.w;
        }
    }

    red[j][col4 * 4 + 0] = a0;
    red[j][col4 * 4 + 1] = a1;
    red[j][col4 * 4 + 2] = a2;
    red[j][col4 * 4 + 3] = a3;
    __syncthreads();

    if (t < 128) {
        double s = 0.0;
        #pragma unroll
        for (int jj = 0; jj < 32; ++jj) s += red[jj][t];
        red[0][t] = s;
    }
    __syncthreads();

    if (t < 64) {
        const int cg = t & 7, k = t >> 3;       // u = cg + 8k
        const double s1 = red[0][cg * 16 + k];
        const double s2 = red[0][cg * 16 + 8 + k];
        const double PN = (double)PPIL * (double)NPTS;
        const double mean = s1 / PN;
        const double var  = s2 / PN - mean * mean;
        const double scale = (double)gamma[t] / sqrt(var + 1e-3);
        const double bias  = (double)beta[t] - mean * scale;
        stats[t]      = (float)scale;
        stats[64 + t] = (float)bias;
    }
}

// ---------------------------------------------------------------------------
// Kernel C: out = relu(rawmax * scale + bias), in place on d_out.
// ---------------------------------------------------------------------------
__global__ __launch_bounds__(256) void pfn_final(
    float* __restrict__ out,
    const float* __restrict__ stats,
    int total4)
{
    const int i = blockIdx.x * blockDim.x + threadIdx.x;
    if (i >= total4) return;
    const int u0 = (i & 15) * 4;     // 4 consecutive channels
    float4 v = ((float4*)out)[i];
    v.x = fmaxf(fmaf(v.x, stats[u0 + 0], stats[64 + u0 + 0]), 0.0f);
    v.y = fmaxf(fmaf(v.y, stats[u0 + 1], stats[64 + u0 + 1]), 0.0f);
    v.z = fmaxf(fmaf(v.z, stats[u0 + 2], stats[64 + u0 + 2]), 0.0f);
    v.w = fmaxf(fmaf(v.w, stats[u0 + 3], stats[64 + u0 + 3]), 0.0f);
    ((float4*)out)[i] = v;
}

// ---------------------------------------------------------------------------
extern "C" void kernel_launch(void* const* d_in, const int* in_sizes, int n_in,
                              void* d_out, int out_size, void* d_ws, size_t ws_size,
                              hipStream_t stream) {
    const float* features   = (const float*)d_in[0];
    const int*   num_voxels = (const int*)d_in[1];
    const int*   coors      = (const int*)d_in[2];
    const float* linear_w   = (const float*)d_in[3];
    const float* gamma      = (const float*)d_in[4];
    const float* beta       = (const float*)d_in[5];
    // d_in[6] = batch_size (unused)

    float* out = (float*)d_out;               // used as rawmax scratch, then finalized
    float* wsf = (float*)d_ws;
    float* partials = wsf;                    // NBLK_A * 128 floats = 640 KB
    float* stats    = wsf + NBLK_A * 128;     // 128 floats

    pfn_main<<<NBLK_A, 256, 0, stream>>>(features, num_voxels, coors, linear_w,
                                         out, partials);
    pfn_stats<<<1, 1024, 0, stream>>>(partials, gamma, beta, stats);

    const int total4 = PPIL * COUT / 4;       // 640000
    pfn_final<<<(total4 + 255) / 256, 256, 0, stream>>>(out, stats, total4);
}

// Round 4
// 41.673 us; speedup vs baseline: 2.0048x; 1.1394x over previous
//
#include <hip/hip_runtime.h>
#include <float.h>
#include <math.h>

#define PPIL   40000
#define NPTS   32
#define CIN    4
#define COUT   64
#define NBLK_A 1250            // PPIL / 32 pillars per block
#define PSTRIDE 132            // floats per pillar in lds_f: 33 float4 (pad 1) -> bank spread

__device__ __forceinline__ float shfl_xor_f(float v, int m) {
    return __shfl_xor(v, m, 64);
}

// ---------------------------------------------------------------------------
// Kernel A: x[n,u] = g_u . f[n] + c_u  (affine factorization of the 9-ch aug)
//   g_u = [w0+w4+w7, w1+w5+w8, w2+w6, w3]   (per block, in lds_w)
//   c_u = -(w4*mx + w5*my + w6*mz + w7*ax + w8*by)  (per pillar-channel)
//   s1[u] = g_u . Fm + nv*c_u  (Fm = masked feature sums, from phase-1 butterfly)
// Outputs: per-pillar raw max -> d_out, per-block s1/s2 partials -> ws.
// ---------------------------------------------------------------------------
__global__ __launch_bounds__(256) void pfn_main(
    const float* __restrict__ features,     // [P][N][4]
    const int*   __restrict__ num_voxels,   // [P]
    const int*   __restrict__ coors,        // [P][4]
    const float* __restrict__ linear_w,     // [64][9]
    float*       __restrict__ rawmax,       // [P][64]  (aliases d_out)
    float*       __restrict__ partials)     // [NBLK_A][128]
{
    __shared__ float lds_f[32 * PSTRIDE];     // masked float4 per point
    __shared__ float lds_pc[32][12];          // {mx,my,mz,ax,by,nvf,Fm0..Fm3}
    __shared__ float lds_w[64 * 9];           // {g0,g1,g2,g3,w4,w5,w6,w7,w8}
    __shared__ float lds_red[4][8][16];

    const int tid = threadIdx.x;
    const int bid = blockIdx.x;
    const int pillar_base = bid * 32;

    // ---- phase 0: per-channel weight prep (threads 0..63) ----
    if (tid < 64) {
        const float* wr = linear_w + tid * 9;
        const float w0 = wr[0], w1 = wr[1], w2 = wr[2], w3 = wr[3], w4 = wr[4];
        const float w5 = wr[5], w6 = wr[6], w7 = wr[7], w8 = wr[8];
        float* dw = &lds_w[tid * 9];
        dw[0] = w0 + w4 + w7;
        dw[1] = w1 + w5 + w8;
        dw[2] = w2 + w6;
        dw[3] = w3;
        dw[4] = w4; dw[5] = w5; dw[6] = w6; dw[7] = w7; dw[8] = w8;
    }

    // ---- phase 1: masked feats -> LDS, pillar constants via butterfly ----
    {
        const int n   = tid & 31;   // point index
        const int pl0 = tid >> 5;   // 0..7
        #pragma unroll
        for (int g = 0; g < 4; ++g) {
            const int pl = g * 8 + pl0;          // 0..31
            const int p  = pillar_base + pl;
            const float4 f = *(const float4*)(features + ((size_t)p * NPTS + n) * CIN);

            const int   nv  = num_voxels[p];
            const float msk = (n < nv) ? 1.0f : 0.0f;
            const float m0 = f.x * msk, m1 = f.y * msk, m2 = f.z * msk, m3 = f.w * msk;

            // butterfly over the 32-lane half: unmasked xyz + masked f0..f3
            float sx = f.x, sy = f.y, sz = f.z;
            float t0 = m0, t1 = m1, t2 = m2, t3 = m3;
            #pragma unroll
            for (int m = 16; m >= 1; m >>= 1) {
                sx += shfl_xor_f(sx, m);
                sy += shfl_xor_f(sy, m);
                sz += shfl_xor_f(sz, m);
                t0 += shfl_xor_f(t0, m);
                t1 += shfl_xor_f(t1, m);
                t2 += shfl_xor_f(t2, m);
                t3 += shfl_xor_f(t3, m);
            }

            *(float4*)&lds_f[pl * PSTRIDE + n * 4] = make_float4(m0, m1, m2, m3);

            if (n == 0) {
                const float inv_nv = 1.0f / (float)nv;
                const int ccy = coors[p * 4 + 2];
                const int ccx = coors[p * 4 + 3];
                float* pc = lds_pc[pl];
                pc[0] = sx * inv_nv;
                pc[1] = sy * inv_nv;
                pc[2] = sz * inv_nv;
                pc[3] = (float)ccx * 0.2f + 0.1f;      // ax
                pc[4] = (float)ccy * 0.2f - 39.9f;     // by
                pc[5] = (float)nv;
                pc[6] = t0; pc[7] = t1; pc[8] = t2; pc[9] = t3;
            }
        }
    }
    __syncthreads();

    // ---- phase 2: 8 threads per pillar, 8 channels each (u = cg + 8k) ----
    const int pl2 = tid >> 3;   // pillar in block, 0..31
    const int cg  = tid & 7;    // channel group

    const float* pc = lds_pc[pl2];
    const float mxp = pc[0], myp = pc[1], mzp = pc[2], axp = pc[3], byp = pc[4];
    const float nvf = pc[5];
    const float Fm0 = pc[6], Fm1 = pc[7], Fm2 = pc[8], Fm3 = pc[9];
    const int   nvi = (int)nvf;

    float g0[8], g1[8], g2[8], g3[8], cc[8];
    #pragma unroll
    for (int k = 0; k < 8; ++k) {
        const float* wp = &lds_w[(cg + 8 * k) * 9];
        g0[k] = wp[0]; g1[k] = wp[1]; g2[k] = wp[2]; g3[k] = wp[3];
        cc[k] = -(wp[4] * mxp + wp[5] * myp + wp[6] * mzp + wp[7] * axp + wp[8] * byp);
    }

    float s2[8], mxa[8];
    #pragma unroll
    for (int k = 0; k < 8; ++k) { s2[k] = 0.0f; mxa[k] = -FLT_MAX; }

    const float4* fb = (const float4*)&lds_f[pl2 * PSTRIDE];
    #pragma unroll 2
    for (int n = 0; n < NPTS; ++n) {
        const float4 f = fb[n];
        const float mskf = (n < nvi) ? 1.0f : 0.0f;
        #pragma unroll
        for (int k = 0; k < 8; ++k) {
            float x = cc[k] * mskf;                 // masked seed; f already masked
            x = fmaf(g0[k], f.x, x);
            x = fmaf(g1[k], f.y, x);
            x = fmaf(g2[k], f.z, x);
            x = fmaf(g3[k], f.w, x);
            s2[k]  = fmaf(x, x, s2[k]);
            mxa[k] = fmaxf(mxa[k], x);
        }
    }

    // factored s1
    float s1[8];
    #pragma unroll
    for (int k = 0; k < 8; ++k) {
        float d = g0[k] * Fm0;
        d = fmaf(g1[k], Fm1, d);
        d = fmaf(g2[k], Fm2, d);
        d = fmaf(g3[k], Fm3, d);
        s1[k] = fmaf(nvf, cc[k], d);
    }

    // raw max -> rawmax (d_out), channel u = cg + 8k
    {
        float* rp = rawmax + (size_t)(pillar_base + pl2) * COUT + cg;
        #pragma unroll
        for (int k = 0; k < 8; ++k) rp[8 * k] = mxa[k];
    }

    // reduce s1/s2 across lanes with equal (lane & 7)
    #pragma unroll
    for (int k = 0; k < 8; ++k) {
        #pragma unroll
        for (int m = 8; m <= 32; m <<= 1) {
            s1[k] += shfl_xor_f(s1[k], m);
            s2[k] += shfl_xor_f(s2[k], m);
        }
    }
    const int lane = tid & 63;
    const int wv   = tid >> 6;
    if (lane < 8) {
        #pragma unroll
        for (int k = 0; k < 8; ++k) {
            lds_red[wv][lane][k]     = s1[k];
            lds_red[wv][lane][8 + k] = s2[k];
        }
    }
    __syncthreads();
    if (tid < 128) {
        const int cg2 = tid >> 4, v = tid & 15;
        const float acc = lds_red[0][cg2][v] + lds_red[1][cg2][v] +
                          lds_red[2][cg2][v] + lds_red[3][cg2][v];
        partials[bid * 128 + tid] = acc;
    }
}

// ---------------------------------------------------------------------------
// Kernel B: parallel reduce of partials (double), finalize BN scale/bias.
// 1024 threads = 32 row-chunks (j = t>>5) x 32 float4-columns (col4 = t&31),
// x4 unrolled so 4 independent float4 loads are in flight (hides L2/L3 lat).
// partial row layout: [cg][k] = sum of channel u=cg+8k, [cg][8+k] = sumsq
// ---------------------------------------------------------------------------
__global__ __launch_bounds__(1024) void pfn_stats(
    const float* __restrict__ partials,
    const float* __restrict__ gamma,
    const float* __restrict__ beta,
    float*       __restrict__ stats)   // scale[64], bias[64]
{
    __shared__ double red[32][128];

    const int t    = threadIdx.x;   // 0..1023
    const int col4 = t & 31;        // float4 column: channels v = col4*4 .. +3
    const int j    = t >> 5;        // row chunk 0..31

    const float4* p4 = (const float4*)partials;   // [NBLK_A][32] float4 rows

    double a0 = 0.0, a1 = 0.0, a2 = 0.0, a3 = 0.0;

    int i = 0;
    for (; i + 4 <= 36; i += 4) {
        const float4 r0 = p4[(j + 32 * (i + 0)) * 32 + col4];
        const float4 r1 = p4[(j + 32 * (i + 1)) * 32 + col4];
        const float4 r2 = p4[(j + 32 * (i + 2)) * 32 + col4];
        const float4 r3 = p4[(j + 32 * (i + 3)) * 32 + col4];
        a0 += (double)r0.x + (double)r1.x + (double)r2.x + (double)r3.x;
        a1 += (double)r0.y + (double)r1.y + (double)r2.y + (double)r3.y;
        a2 += (double)r0.z + (double)r1.z + (double)r2.z + (double)r3.z;
        a3 += (double)r0.w + (double)r1.w + (double)r2.w + (double)r3.w;
    }
    for (; i < 40; ++i) {
        const int b = j + 32 * i;
        if (b < NBLK_A) {
            const float4 r = p4[b * 32 + col4];
            a0 += (double)r.x; a1 += (double)r.y;
            a2 += (double)r.z; a3 += (double)r.w;
        }
    }

    red[j][col4 * 4 + 0] = a0;
    red[j][col4 * 4 + 1] = a1;
    red[j][col4 * 4 + 2] = a2;
    red[j][col4 * 4 + 3] = a3;
    __syncthreads();

    if (t < 128) {
        double s = 0.0;
        #pragma unroll
        for (int jj = 0; jj < 32; ++jj) s += red[jj][t];
        red[0][t] = s;
    }
    __syncthreads();

    if (t < 64) {
        const int cg = t & 7, k = t >> 3;       // u = cg + 8k
        const double s1 = red[0][cg * 16 + k];
        const double s2 = red[0][cg * 16 + 8 + k];
        const double PN = (double)PPIL * (double)NPTS;
        const double mean = s1 / PN;
        const double var  = s2 / PN - mean * mean;
        const double scale = (double)gamma[t] / sqrt(var + 1e-3);
        const double bias  = (double)beta[t] - mean * scale;
        stats[t]      = (float)scale;
        stats[64 + t] = (float)bias;
    }
}

// ---------------------------------------------------------------------------
// Kernel C: out = relu(rawmax * scale + bias), in place on d_out.
// ---------------------------------------------------------------------------
__global__ __launch_bounds__(256) void pfn_final(
    float* __restrict__ out,
    const float* __restrict__ stats,
    int total4)
{
    const int i = blockIdx.x * blockDim.x + threadIdx.x;
    if (i >= total4) return;
    const int u0 = (i & 15) * 4;     // 4 consecutive channels
    float4 v = ((float4*)out)[i];
    v.x = fmaxf(fmaf(v.x, stats[u0 + 0], stats[64 + u0 + 0]), 0.0f);
    v.y = fmaxf(fmaf(v.y, stats[u0 + 1], stats[64 + u0 + 1]), 0.0f);
    v.z = fmaxf(fmaf(v.z, stats[u0 + 2], stats[64 + u0 + 2]), 0.0f);
    v.w = fmaxf(fmaf(v.w, stats[u0 + 3], stats[64 + u0 + 3]), 0.0f);
    ((float4*)out)[i] = v;
}

// ---------------------------------------------------------------------------
extern "C" void kernel_launch(void* const* d_in, const int* in_sizes, int n_in,
                              void* d_out, int out_size, void* d_ws, size_t ws_size,
                              hipStream_t stream) {
    const float* features   = (const float*)d_in[0];
    const int*   num_voxels = (const int*)d_in[1];
    const int*   coors      = (const int*)d_in[2];
    const float* linear_w   = (const float*)d_in[3];
    const float* gamma      = (const float*)d_in[4];
    const float* beta       = (const float*)d_in[5];
    // d_in[6] = batch_size (unused)

    float* out = (float*)d_out;               // used as rawmax scratch, then finalized
    float* wsf = (float*)d_ws;
    float* partials = wsf;                    // NBLK_A * 128 floats = 640 KB
    float* stats    = wsf + NBLK_A * 128;     // 128 floats

    pfn_main<<<NBLK_A, 256, 0, stream>>>(features, num_voxels, coors, linear_w,
                                         out, partials);
    pfn_stats<<<1, 1024, 0, stream>>>(partials, gamma, beta, stats);

    const int total4 = PPIL * COUT / 4;       // 640000
    pfn_final<<<(total4 + 255) / 256, 256, 0, stream>>>(out, stats, total4);
}

// Round 5
// 33.099 us; speedup vs baseline: 2.5241x; 1.2590x over previous
//
#include <hip/hip_runtime.h>
#include <float.h>
#include <math.h>

#define PPIL   40000
#define NPTS   32
#define COUT   64
#define PPB    16              // pillars per main block
#define NBLK_A 2500            // PPIL / PPB
#define PSTRIDE 132            // floats per pillar slot (33 float4: bank spread)
#define NSB    16              // stats reduce blocks

__device__ __forceinline__ float shfl_xor_f(float v, int m) {
    return __shfl_xor(v, m, 64);
}

// ---------------------------------------------------------------------------
// Kernel A: x[n,u] = g_u . f[n] + c_u  (affine factorization, unmasked staging)
// Phase 1: coalesced unmasked float4 stage (no shuffles).
// Tree:    8 thr/pillar sum 4 points each (unmasked xyz + masked f0..3),
//          3-round shfl_xor over the 8-group (21 bpermutes vs 140 before).
// Phase 2: 8 thr/pillar x 8 ch, 7 VALU ops per point-channel; factored s1.
// ---------------------------------------------------------------------------
__global__ __launch_bounds__(128) void pfn_main(
    const float* __restrict__ features,     // [P][N][4]
    const int*   __restrict__ num_voxels,   // [P]
    const int*   __restrict__ coors,        // [P][4]
    const float* __restrict__ linear_w,     // [64][9]
    float*       __restrict__ rawmax,       // [P][64]  (aliases d_out)
    float*       __restrict__ partials)     // [NBLK_A][128]
{
    __shared__ float lds_f[PPB * PSTRIDE];    // unmasked float4 per point
    __shared__ float lds_pc[PPB][12];         // {mx,my,mz,ax,by,nvf,Fm0..Fm3}
    __shared__ float lds_w[64 * 9];           // {g0,g1,g2,g3,w4,w5,w6,w7,w8}
    __shared__ float lds_red[2][8][16];

    const int tid = threadIdx.x;   // 0..127
    const int bid = blockIdx.x;
    const int pb  = bid * PPB;

    // ---- weight prep (threads 0..63) ----
    if (tid < 64) {
        const float* wr = linear_w + tid * 9;
        const float w0 = wr[0], w1 = wr[1], w2 = wr[2], w3 = wr[3], w4 = wr[4];
        const float w5 = wr[5], w6 = wr[6], w7 = wr[7], w8 = wr[8];
        float* dw = &lds_w[tid * 9];
        dw[0] = w0 + w4 + w7;
        dw[1] = w1 + w5 + w8;
        dw[2] = w2 + w6;
        dw[3] = w3;
        dw[4] = w4; dw[5] = w5; dw[6] = w6; dw[7] = w7; dw[8] = w8;
    }

    // ---- per-pillar scalars ----
    if (tid < PPB) {
        const int p = pb + tid;
        lds_pc[tid][3] = (float)coors[p * 4 + 3] * 0.2f + 0.1f;    // ax
        lds_pc[tid][4] = (float)coors[p * 4 + 2] * 0.2f - 39.9f;   // by
        lds_pc[tid][5] = (float)num_voxels[p];
    }

    // ---- phase 1: coalesced unmasked stage ----
    #pragma unroll
    for (int j = 0; j < 4; ++j) {
        const int idx = tid + 128 * j;        // 0..511 point slot in block
        const int pl  = idx >> 5, n = idx & 31;
        const float4 f = *(const float4*)(features + ((size_t)(pb + pl) * NPTS + n) * 4);
        *(float4*)&lds_f[pl * PSTRIDE + n * 4] = f;
    }
    __syncthreads();

    // ---- pillar-sum tree: 8 threads per pillar, 4 points each ----
    {
        const int pl = tid >> 3, sub = tid & 7;
        const int nv = (int)lds_pc[pl][5];
        float sx = 0.f, sy = 0.f, sz = 0.f;
        float t0 = 0.f, t1 = 0.f, t2 = 0.f, t3 = 0.f;
        #pragma unroll
        for (int i = 0; i < 4; ++i) {
            const int n = sub + 8 * i;
            const float4 f = *(const float4*)&lds_f[pl * PSTRIDE + n * 4];
            sx += f.x; sy += f.y; sz += f.z;
            const float m = (n < nv) ? 1.0f : 0.0f;
            t0 = fmaf(f.x, m, t0); t1 = fmaf(f.y, m, t1);
            t2 = fmaf(f.z, m, t2); t3 = fmaf(f.w, m, t3);
        }
        #pragma unroll
        for (int m = 1; m <= 4; m <<= 1) {
            sx += shfl_xor_f(sx, m); sy += shfl_xor_f(sy, m); sz += shfl_xor_f(sz, m);
            t0 += shfl_xor_f(t0, m); t1 += shfl_xor_f(t1, m);
            t2 += shfl_xor_f(t2, m); t3 += shfl_xor_f(t3, m);
        }
        if (sub == 0) {
            const float inv = 1.0f / lds_pc[pl][5];
            lds_pc[pl][0] = sx * inv;
            lds_pc[pl][1] = sy * inv;
            lds_pc[pl][2] = sz * inv;
            lds_pc[pl][6] = t0; lds_pc[pl][7] = t1;
            lds_pc[pl][8] = t2; lds_pc[pl][9] = t3;
        }
    }
    __syncthreads();

    // ---- phase 2: pillar pl2 = tid>>3, channel group cg = tid&7 ----
    const int pl2 = tid >> 3;   // 0..15
    const int cg  = tid & 7;

    const float* pc = lds_pc[pl2];
    const float mxp = pc[0], myp = pc[1], mzp = pc[2], axp = pc[3], byp = pc[4];
    const float nvf = pc[5];
    const float Fm0 = pc[6], Fm1 = pc[7], Fm2 = pc[8], Fm3 = pc[9];
    const int   nvi = (int)nvf;

    float g0[8], g1[8], g2[8], g3[8], cc[8];
    #pragma unroll
    for (int k = 0; k < 8; ++k) {
        const float* wp = &lds_w[(cg + 8 * k) * 9];
        g0[k] = wp[0]; g1[k] = wp[1]; g2[k] = wp[2]; g3[k] = wp[3];
        cc[k] = -(wp[4] * mxp + wp[5] * myp + wp[6] * mzp + wp[7] * axp + wp[8] * byp);
    }

    float s2[8], mxa[8];
    #pragma unroll
    for (int k = 0; k < 8; ++k) { s2[k] = 0.0f; mxa[k] = -FLT_MAX; }

    const float4* fb = (const float4*)&lds_f[pl2 * PSTRIDE];
    #pragma unroll 2
    for (int n = 0; n < NPTS; ++n) {
        const float4 f = fb[n];
        const float mskf = (n < nvi) ? 1.0f : 0.0f;
        #pragma unroll
        for (int k = 0; k < 8; ++k) {
            float x = cc[k];                      // unmasked affine
            x = fmaf(g0[k], f.x, x);
            x = fmaf(g1[k], f.y, x);
            x = fmaf(g2[k], f.z, x);
            x = fmaf(g3[k], f.w, x);
            x *= mskf;                            // exact 0 for masked rows
            s2[k]  = fmaf(x, x, s2[k]);
            mxa[k] = fmaxf(mxa[k], x);
        }
    }

    // factored s1 over this pillar
    float s1[8];
    #pragma unroll
    for (int k = 0; k < 8; ++k) {
        float d = g0[k] * Fm0;
        d = fmaf(g1[k], Fm1, d);
        d = fmaf(g2[k], Fm2, d);
        d = fmaf(g3[k], Fm3, d);
        s1[k] = fmaf(nvf, cc[k], d);
    }

    // raw max -> rawmax (d_out), channel u = cg + 8k
    {
        float* rp = rawmax + (size_t)(pb + pl2) * COUT + cg;
        #pragma unroll
        for (int k = 0; k < 8; ++k) rp[8 * k] = mxa[k];
    }

    // reduce s1/s2 across the 8 pillars of each wave (masks 8,16,32)
    #pragma unroll
    for (int k = 0; k < 8; ++k) {
        #pragma unroll
        for (int m = 8; m <= 32; m <<= 1) {
            s1[k] += shfl_xor_f(s1[k], m);
            s2[k] += shfl_xor_f(s2[k], m);
        }
    }
    const int lane = tid & 63;
    const int wv   = tid >> 6;
    if (lane < 8) {
        #pragma unroll
        for (int k = 0; k < 8; ++k) {
            lds_red[wv][lane][k]     = s1[k];
            lds_red[wv][lane][8 + k] = s2[k];
        }
    }
    __syncthreads();
    // partials column layout: cg*16 + k -> s1 of u=cg+8k ; cg*16+8+k -> s2
    {
        const int cg2 = tid >> 4, v = tid & 15;
        partials[bid * 128 + tid] = lds_red[0][cg2][v] + lds_red[1][cg2][v];
    }
}

// ---------------------------------------------------------------------------
// Kernel B: 16 blocks, each reduces rows r = b + 16*m of partials (double),
// writes partials2[b][128] (float). No cross-block combine here.
// ---------------------------------------------------------------------------
__global__ __launch_bounds__(1024) void pfn_stats16(
    const float* __restrict__ partials,
    float*       __restrict__ partials2)    // [NSB][128]
{
    __shared__ double red[32][128];

    const int t    = threadIdx.x;   // 0..1023
    const int b    = blockIdx.x;    // 0..15
    const int col4 = t & 31;
    const int j    = t >> 5;        // 0..31

    const float4* p4 = (const float4*)partials;   // [NBLK_A][32] float4

    double a0 = 0.0, a1 = 0.0, a2 = 0.0, a3 = 0.0;
    #pragma unroll
    for (int i = 0; i < 5; ++i) {
        const int m = j + 32 * i;
        const int r = b + 16 * m;
        if (r < NBLK_A) {
            const float4 v = p4[r * 32 + col4];
            a0 += (double)v.x; a1 += (double)v.y;
            a2 += (double)v.z; a3 += (double)v.w;
        }
    }
    red[j][col4 * 4 + 0] = a0;
    red[j][col4 * 4 + 1] = a1;
    red[j][col4 * 4 + 2] = a2;
    red[j][col4 * 4 + 3] = a3;
    __syncthreads();

    if (t < 128) {
        double s = 0.0;
        #pragma unroll
        for (int jj = 0; jj < 32; ++jj) s += red[jj][t];
        partials2[b * 128 + t] = (float)s;
    }
}

// ---------------------------------------------------------------------------
// Kernel C: per-block redundant combine of partials2 (8 KB, L2/L3-hot) ->
// scale/bias in LDS, then out = relu(rawmax*scale+bias) in place.
// ---------------------------------------------------------------------------
__global__ __launch_bounds__(256) void pfn_final(
    const float* __restrict__ partials2,
    const float* __restrict__ gamma,
    const float* __restrict__ beta,
    float*       __restrict__ out)
{
    __shared__ double red[128];
    __shared__ float  sb[128];      // scale[64], bias[64]

    const int t = threadIdx.x;
    if (t < 128) {
        double s = 0.0;
        #pragma unroll
        for (int b = 0; b < NSB; ++b) s += (double)partials2[b * 128 + t];
        red[t] = s;
    }
    __syncthreads();
    if (t < 64) {
        const int cg = t & 7, k = t >> 3;       // u = cg + 8k
        const double s1 = red[cg * 16 + k];
        const double s2 = red[cg * 16 + 8 + k];
        const double PN = (double)PPIL * (double)NPTS;
        const double mean = s1 / PN;
        const double var  = s2 / PN - mean * mean;
        const double scale = (double)gamma[t] / sqrt(var + 1e-3);
        sb[t]      = (float)scale;
        sb[64 + t] = (float)((double)beta[t] - mean * scale);
    }
    __syncthreads();

    const int i  = blockIdx.x * 256 + t;   // exactly 640000 = 2500*256
    const int u0 = (i & 15) * 4;           // 4 consecutive channels
    float4 v = ((const float4*)out)[i];
    v.x = fmaxf(fmaf(v.x, sb[u0 + 0], sb[64 + u0 + 0]), 0.0f);
    v.y = fmaxf(fmaf(v.y, sb[u0 + 1], sb[64 + u0 + 1]), 0.0f);
    v.z = fmaxf(fmaf(v.z, sb[u0 + 2], sb[64 + u0 + 2]), 0.0f);
    v.w = fmaxf(fmaf(v.w, sb[u0 + 3], sb[64 + u0 + 3]), 0.0f);
    ((float4*)out)[i] = v;
}

// ---------------------------------------------------------------------------
extern "C" void kernel_launch(void* const* d_in, const int* in_sizes, int n_in,
                              void* d_out, int out_size, void* d_ws, size_t ws_size,
                              hipStream_t stream) {
    const float* features   = (const float*)d_in[0];
    const int*   num_voxels = (const int*)d_in[1];
    const int*   coors      = (const int*)d_in[2];
    const float* linear_w   = (const float*)d_in[3];
    const float* gamma      = (const float*)d_in[4];
    const float* beta       = (const float*)d_in[5];
    // d_in[6] = batch_size (unused)

    float* out = (float*)d_out;               // rawmax scratch, finalized in place
    float* wsf = (float*)d_ws;
    float* partials  = wsf;                   // NBLK_A*128 floats = 1.28 MB
    float* partials2 = wsf + NBLK_A * 128;    // NSB*128 floats

    pfn_main<<<NBLK_A, 128, 0, stream>>>(features, num_voxels, coors, linear_w,
                                         out, partials);
    pfn_stats16<<<NSB, 1024, 0, stream>>>(partials, partials2);
    pfn_final<<<NBLK_A, 256, 0, stream>>>(partials2, gamma, beta, out);
}